// Round 11
// baseline (59.153 us; speedup 1.0000x reference)
//
#include <hip/hip_runtime.h>

// (min,+) DP with wave specialization. 5 waves/block per image:
//   waves 1-4: prep = softplus + row-cumsum S for an 8-row chunk -> LDS,
//              with next-chunk loads software-pipelined (issued before
//              current chunk's compute) so load latency hides under
//              compute + barrier wait.
//   wave 0:    serial vchain recurrence at s_setprio(1) (critical path;
//              prep waves park at barriers, chain owns the SIMD).
// CH=8: prep-per-chunk << chain-per-chunk, so the chain never waits after
// chunk 0. LDS 2x8x1KB = 16KB -> 2 blocks/CU co-reside.

#define HH 256
#define WW 256
#define CH 8           // rows per chunk
#define NCH 32         // chunks per image
#define NULLV 1e30f

#define SBAR() __builtin_amdgcn_sched_barrier(0)

template<int CTRL, int ROWM>
__device__ __forceinline__ float dpp_mov(float x, float oldv) {
    return __builtin_bit_cast(float, __builtin_amdgcn_update_dpp(
        __builtin_bit_cast(int, oldv), __builtin_bit_cast(int, x),
        CTRL, ROWM, 0xF, false));
}

__device__ __forceinline__ float wave_iscan_add(float x) {
    x += dpp_mov<0x111, 0xF>(x, 0.0f);  // row_shr:1
    x += dpp_mov<0x112, 0xF>(x, 0.0f);  // row_shr:2
    x += dpp_mov<0x114, 0xF>(x, 0.0f);  // row_shr:4
    x += dpp_mov<0x118, 0xF>(x, 0.0f);  // row_shr:8
    x += dpp_mov<0x142, 0xA>(x, 0.0f);  // row_bcast:15 -> rows 1,3
    x += dpp_mov<0x143, 0xC>(x, 0.0f);  // row_bcast:31 -> rows 2,3
    return x;
}

__device__ __forceinline__ float wave_iscan_min(float x) {
    x = fminf(x, dpp_mov<0x111, 0xF>(x, NULLV));
    x = fminf(x, dpp_mov<0x112, 0xF>(x, NULLV));
    x = fminf(x, dpp_mov<0x114, 0xF>(x, NULLV));
    x = fminf(x, dpp_mov<0x118, 0xF>(x, NULLV));
    x = fminf(x, dpp_mov<0x142, 0xA>(x, NULLV));
    x = fminf(x, dpp_mov<0x143, 0xC>(x, NULLV));
    return x;
}

__device__ __forceinline__ float softplus_f(float x) {
    float ax = fabsf(x);
    float t  = __expf(-ax);
    return fmaxf(x, 0.0f) + __logf(1.0f + t);
}

// full-row cumsum of softplus for one row; returns S at cols 4l..4l+3
__device__ __forceinline__ float4 prep_row(float4 c) {
    float t0 = softplus_f(c.x);
    float t1 = t0 + softplus_f(c.y);
    float t2 = t1 + softplus_f(c.z);
    float t3 = t2 + softplus_f(c.w);
    float s    = wave_iscan_add(t3);
    float soff = dpp_mov<0x138, 0xF>(s, 0.0f);  // wave_shr:1, lane0 -> 0
    return make_float4(soff + t0, soff + t1, soff + t2, soff + t3);
}

__global__ __launch_bounds__(320, 2) void dp_kernel(const float* __restrict__ img,
                                                    float* __restrict__ out) {
    const int tid = threadIdx.x;
    const int wid = tid >> 6;      // 0 = chain wave, 1..4 = prep waves
    const int lane = tid & 63;

    __shared__ __align__(16) float sbuf[2][CH][WW];   // 16 KB double buffer

    const float* gbase = img + (size_t)blockIdx.x * HH * WW;

    if (wid == 0) {
        // ---------------- chain wave (critical path) ----------------
        __builtin_amdgcn_s_setprio(1);
        float v0, v1, v2, v3;

        auto row_step = [&](const float4& S) {
            float soff = dpp_mov<0x138, 0xF>(S.w, 0.0f);  // S[4l-1]
            float vm1  = dpp_mov<0x138, 0xF>(v3, NULLV);  // v[4l-1]
            float B0 = fminf(v0, vm1) - soff;
            float B1 = fminf(v1, v0) - S.x;
            float B2 = fminf(v2, v1) - S.y;
            float B3 = fminf(v3, v2) - S.z;
            float m1 = fminf(B0, B1);
            float m2 = fminf(m1, B2);
            float m3 = fminf(m2, B3);
            float mm   = wave_iscan_min(m3);
            float moff = dpp_mov<0x138, 0xF>(mm, NULLV);
            v0 = S.x + fminf(moff, B0);
            v1 = S.y + fminf(moff, m1);
            v2 = S.z + fminf(moff, m2);
            v3 = S.w + fminf(moff, m3);
        };

#define RD(buf, i) (*reinterpret_cast<const float4*>(&(buf)[i][lane * 4]))

        // chunk 0 (peel row-0 init)
        __syncthreads();
        {
            const float(*buf)[WW] = sbuf[0];
            float4 S0r = RD(buf, 0);
            float4 Sc = RD(buf, 1), Sn = RD(buf, 2);
            v0 = S0r.x; v1 = S0r.y; v2 = S0r.z; v3 = S0r.w;
#pragma unroll
            for (int i = 1; i < CH; ++i) {
                float4 Sn2 = (i + 2 < CH) ? RD(buf, i + 2) : Sn;
                row_step(Sc);
                Sc = Sn; Sn = Sn2;
            }
        }
        // chunks 1..31
        for (int k = 1; k < NCH; ++k) {
            __syncthreads();
            const float(*buf)[WW] = sbuf[k & 1];
            float4 Sc = RD(buf, 0), Sn = RD(buf, 1);
#pragma unroll
            for (int i = 0; i < CH; ++i) {
                float4 Sn2 = (i + 2 < CH) ? RD(buf, i + 2) : Sn;
                row_step(Sc);
                Sc = Sn; Sn = Sn2;
            }
        }
#undef RD
        if (lane == 63) out[blockIdx.x] = v3;
    } else {
        // ---------------- prep waves ----------------
        const int pw = wid - 1;                    // 0..3, 2 rows each/chunk
        const float4* gp = reinterpret_cast<const float4*>(gbase) + lane;
        const int lb = pw * 2;

        // preload chunk 0's rows
        float4 La = gp[(size_t)(pw * 2 + 0) * 64];
        float4 Lb = gp[(size_t)(pw * 2 + 1) * 64];
        SBAR();

        for (int k = 0; k < NCH; ++k) {
            // issue next chunk's loads BEFORE computing current (pipelined)
            float4 Na = La, Nb = Lb;
            if (k + 1 < NCH) {
                const int rn = (k + 1) * CH + pw * 2;
                Na = gp[(size_t)(rn + 0) * 64];
                Nb = gp[(size_t)(rn + 1) * 64];
            }
            SBAR();
            float(*buf)[WW] = sbuf[k & 1];
            *reinterpret_cast<float4*>(&buf[lb + 0][lane * 4]) = prep_row(La);
            *reinterpret_cast<float4*>(&buf[lb + 1][lane * 4]) = prep_row(Lb);
            __syncthreads();                       // publish chunk k
            La = Na; Lb = Nb;
        }
    }
}

extern "C" void kernel_launch(void* const* d_in, const int* in_sizes, int n_in,
                              void* d_out, int out_size, void* d_ws, size_t ws_size,
                              hipStream_t stream) {
    const float* img = (const float*)d_in[0];
    float* out = (float*)d_out;
    dp_kernel<<<out_size, 320, 0, stream>>>(img, out);
}

// Round 12
// 54.823 us; speedup vs baseline: 1.0790x; 1.0790x over previous
//
#include <hip/hip_runtime.h>

// (min,+) DP, wave-specialized, MINIMAL block: 3 waves/image.
//   wave 0:    serial vchain; whole 8-row chunk read into registers up-front
//              (8 outstanding ds_read_b128 -> no LDS latency on the chain).
//   waves 1-2: prep = softplus + row-cumsum for 4 rows each per chunk,
//              next-chunk loads issued before current compute (loop-carried,
//              can't sink past __syncthreads).
// 3 waves/block => ~1.5 waves/SIMD: probes whether the chain's ~550cyc/row
// is co-residency arbitration (should drop) or intrinsic chain latency.

#define HH 256
#define WW 256
#define CH 8           // rows per chunk
#define NCH 32         // chunks per image
#define NULLV 1e30f

#define SBAR() __builtin_amdgcn_sched_barrier(0)

template<int CTRL, int ROWM>
__device__ __forceinline__ float dpp_mov(float x, float oldv) {
    return __builtin_bit_cast(float, __builtin_amdgcn_update_dpp(
        __builtin_bit_cast(int, oldv), __builtin_bit_cast(int, x),
        CTRL, ROWM, 0xF, false));
}

__device__ __forceinline__ float wave_iscan_add(float x) {
    x += dpp_mov<0x111, 0xF>(x, 0.0f);  // row_shr:1
    x += dpp_mov<0x112, 0xF>(x, 0.0f);  // row_shr:2
    x += dpp_mov<0x114, 0xF>(x, 0.0f);  // row_shr:4
    x += dpp_mov<0x118, 0xF>(x, 0.0f);  // row_shr:8
    x += dpp_mov<0x142, 0xA>(x, 0.0f);  // row_bcast:15 -> rows 1,3
    x += dpp_mov<0x143, 0xC>(x, 0.0f);  // row_bcast:31 -> rows 2,3
    return x;
}

__device__ __forceinline__ float wave_iscan_min(float x) {
    x = fminf(x, dpp_mov<0x111, 0xF>(x, NULLV));
    x = fminf(x, dpp_mov<0x112, 0xF>(x, NULLV));
    x = fminf(x, dpp_mov<0x114, 0xF>(x, NULLV));
    x = fminf(x, dpp_mov<0x118, 0xF>(x, NULLV));
    x = fminf(x, dpp_mov<0x142, 0xA>(x, NULLV));
    x = fminf(x, dpp_mov<0x143, 0xC>(x, NULLV));
    return x;
}

__device__ __forceinline__ float softplus_f(float x) {
    float ax = fabsf(x);
    float t  = __expf(-ax);
    return fmaxf(x, 0.0f) + __logf(1.0f + t);
}

// full-row cumsum of softplus for one row; returns S at cols 4l..4l+3
__device__ __forceinline__ float4 prep_row(float4 c) {
    float t0 = softplus_f(c.x);
    float t1 = t0 + softplus_f(c.y);
    float t2 = t1 + softplus_f(c.z);
    float t3 = t2 + softplus_f(c.w);
    float s    = wave_iscan_add(t3);
    float soff = dpp_mov<0x138, 0xF>(s, 0.0f);  // wave_shr:1, lane0 -> 0
    return make_float4(soff + t0, soff + t1, soff + t2, soff + t3);
}

__global__ __launch_bounds__(192, 2) void dp_kernel(const float* __restrict__ img,
                                                    float* __restrict__ out) {
    const int tid = threadIdx.x;
    const int wid = tid >> 6;      // 0 = chain wave, 1..2 = prep waves
    const int lane = tid & 63;

    __shared__ __align__(16) float sbuf[2][CH][WW];   // 16 KB double buffer

    const float* gbase = img + (size_t)blockIdx.x * HH * WW;

    if (wid == 0) {
        // ---------------- chain wave (critical path) ----------------
        __builtin_amdgcn_s_setprio(1);
        float v0, v1, v2, v3;

        auto row_step = [&](const float4& S) {
            float soff = dpp_mov<0x138, 0xF>(S.w, 0.0f);  // S[4l-1]
            float vm1  = dpp_mov<0x138, 0xF>(v3, NULLV);  // v[4l-1]
            float B0 = fminf(v0, vm1) - soff;
            float B1 = fminf(v1, v0) - S.x;
            float B2 = fminf(v2, v1) - S.y;
            float B3 = fminf(v3, v2) - S.z;
            float m1 = fminf(B0, B1);
            float m2 = fminf(m1, B2);
            float m3 = fminf(m2, B3);
            float mm   = wave_iscan_min(m3);
            float moff = dpp_mov<0x138, 0xF>(mm, NULLV);
            v0 = S.x + fminf(moff, B0);
            v1 = S.y + fminf(moff, m1);
            v2 = S.z + fminf(moff, m2);
            v3 = S.w + fminf(moff, m3);
        };

#define RD(buf, i) (*reinterpret_cast<const float4*>(&(buf)[i][lane * 4]))

        // chunk 0 (peel row-0 init); whole chunk -> registers first
        __syncthreads();
        {
            const float(*buf)[WW] = sbuf[0];
            float4 R0 = RD(buf, 0), R1 = RD(buf, 1), R2 = RD(buf, 2),
                   R3 = RD(buf, 3), R4 = RD(buf, 4), R5 = RD(buf, 5),
                   R6 = RD(buf, 6), R7 = RD(buf, 7);
            v0 = R0.x; v1 = R0.y; v2 = R0.z; v3 = R0.w;
            row_step(R1); row_step(R2); row_step(R3); row_step(R4);
            row_step(R5); row_step(R6); row_step(R7);
        }
        // chunks 1..31
        for (int k = 1; k < NCH; ++k) {
            __syncthreads();
            const float(*buf)[WW] = sbuf[k & 1];
            float4 R0 = RD(buf, 0), R1 = RD(buf, 1), R2 = RD(buf, 2),
                   R3 = RD(buf, 3), R4 = RD(buf, 4), R5 = RD(buf, 5),
                   R6 = RD(buf, 6), R7 = RD(buf, 7);
            row_step(R0); row_step(R1); row_step(R2); row_step(R3);
            row_step(R4); row_step(R5); row_step(R6); row_step(R7);
        }
#undef RD
        if (lane == 63) out[blockIdx.x] = v3;
    } else {
        // ---------------- prep waves (2 waves x 4 rows/chunk) ----------------
        const int pw = wid - 1;                    // 0..1
        const float4* gp = reinterpret_cast<const float4*>(gbase) + lane;
        const int lb = pw * 4;

        // preload chunk 0's rows
        float4 L0 = gp[(size_t)(lb + 0) * 64];
        float4 L1 = gp[(size_t)(lb + 1) * 64];
        float4 L2 = gp[(size_t)(lb + 2) * 64];
        float4 L3 = gp[(size_t)(lb + 3) * 64];
        SBAR();

        for (int k = 0; k < NCH; ++k) {
            // issue next chunk's loads BEFORE computing current (loop-carried;
            // cannot sink past the __syncthreads below)
            float4 N0 = L0, N1 = L1, N2 = L2, N3 = L3;
            if (k + 1 < NCH) {
                const int rn = (k + 1) * CH + lb;
                N0 = gp[(size_t)(rn + 0) * 64];
                N1 = gp[(size_t)(rn + 1) * 64];
                N2 = gp[(size_t)(rn + 2) * 64];
                N3 = gp[(size_t)(rn + 3) * 64];
            }
            SBAR();
            float(*buf)[WW] = sbuf[k & 1];
            *reinterpret_cast<float4*>(&buf[lb + 0][lane * 4]) = prep_row(L0);
            *reinterpret_cast<float4*>(&buf[lb + 1][lane * 4]) = prep_row(L1);
            *reinterpret_cast<float4*>(&buf[lb + 2][lane * 4]) = prep_row(L2);
            *reinterpret_cast<float4*>(&buf[lb + 3][lane * 4]) = prep_row(L3);
            __syncthreads();                       // publish chunk k
            L0 = N0; L1 = N1; L2 = N2; L3 = N3;
        }
    }
}

extern "C" void kernel_launch(void* const* d_in, const int* in_sizes, int n_in,
                              void* d_out, int out_size, void* d_ws, size_t ws_size,
                              hipStream_t stream) {
    const float* img = (const float*)d_in[0];
    float* out = (float*)d_out;
    dp_kernel<<<out_size, 192, 0, stream>>>(img, out);
}